// Round 9
// baseline (274.498 us; speedup 1.0000x reference)
//
#include <hip/hip_runtime.h>
#include <hip/hip_bf16.h>

typedef __hip_bfloat16 bf16;
typedef short short8 __attribute__((ext_vector_type(8)));
typedef float f32x4 __attribute__((ext_vector_type(4)));
typedef float f32x16 __attribute__((ext_vector_type(16)));

#define GLOBAL_AS __attribute__((address_space(1)))
#define LDS_AS __attribute__((address_space(3)))

__device__ inline unsigned short f2bf(float x) {
    union { float f; unsigned u; } v; v.f = x;
    unsigned r = v.u + 0x7fffu + ((v.u >> 16) & 1u);
    return (unsigned short)(r >> 16);
}

__device__ inline unsigned pkbf(float a, float b) {
    float2 f; f.x = a; f.y = b;
    union { __hip_bfloat162 h; unsigned u; } c;
    c.h = __float22bfloat162_rn(f);
    return c.u;
}

__device__ inline float fast_exp2(float x) {
#if __has_builtin(__builtin_amdgcn_exp2f)
    return __builtin_amdgcn_exp2f(x);
#else
    return exp2f(x);
#endif
}

// async global->LDS, 16 B per lane; LDS dest = wave-uniform base + lane*16
__device__ inline void async16(const void* g, void* l) {
    __builtin_amdgcn_global_load_lds((const GLOBAL_AS void*)g, (LDS_AS void*)l, 16, 0, 0);
}

// ---------------- fused prep: cvt x->bf16 + both weight transposes ----------------
// ROUND-9: one kernel replaces cvt_f32_bf16 + 2x transpose_bf16. Saves 2 launch
// boundaries and co-schedules the memory-bound block populations (tail fill).
// Block ranges: [0,8192) cvt; [8192,11264) w_attn T (96x32); [11264,12288) w_proj T.

__global__ __launch_bounds__(256) void prep_fused(const float* __restrict__ x,
                                                  unsigned short* __restrict__ xb,
                                                  const float* __restrict__ wa,
                                                  unsigned short* __restrict__ waT,
                                                  const float* __restrict__ wp,
                                                  unsigned short* __restrict__ wpT) {
    __shared__ float s[32][33];
    const int blk = blockIdx.x;
    if (blk < 8192) {
        int i = blk * 256 + threadIdx.x;
        float4 v = ((const float4*)x)[i];
        ushort4 o;
        o.x = f2bf(v.x); o.y = f2bf(v.y); o.z = f2bf(v.z); o.w = f2bf(v.w);
        ((ushort4*)xb)[i] = o;
        return;
    }
    const float* in;
    unsigned short* out;
    int R = 1024, Cc, c0, r0;
    if (blk < 11264) {
        int p = blk - 8192;
        in = wa; out = waT; Cc = 3072;
        c0 = (p % 96) * 32; r0 = (p / 96) * 32;
    } else {
        int p = blk - 11264;
        in = wp; out = wpT; Cc = 1024;
        c0 = (p & 31) * 32; r0 = (p >> 5) * 32;
    }
    int tx = threadIdx.x & 31, ty = threadIdx.x >> 5;
#pragma unroll
    for (int i = 0; i < 4; i++)
        s[ty + i * 8][tx] = in[(size_t)(r0 + ty + i * 8) * Cc + c0 + tx];
    __syncthreads();
#pragma unroll
    for (int i = 0; i < 4; i++)
        out[(size_t)(c0 + ty + i * 8) * R + r0 + tx] = f2bf(s[tx][ty + i * 8]);
}

// ---------------- QKV GEMM: 256x128 tile, 512 thr ----------------
// C[m][n] = sum_k A[m][k] * Bt[n][k], K=1024. Q/K -> [B,H,N,D] bf16 (Q scaled),
// V -> TRANSPOSED [B,H,D,N] bf16. Grid (24, 32): bn<8 Q, <16 K, <24 V.
// ROUND-9: m-tile doubled to 256 with 8 waves (wm=(w>>1)*64 in {0,64,128,192},
// wn=(w&1)*64). Mechanism: barrier pairs per output FLOP halve (the 2-barrier
// structure's known ~20% stall), A-panel staging traffic serves 2x output
// (806->605 MB total), staging instrs/thread 8->6. Inner loop, swizzle, and
// per-output MFMA accumulation order are byte-identical to the verified kernel
// -> bit-identical results. Epilogues run 2 passes of 128 rows (MODE1 pattern);
// index edits are mechanical (&127, +pass*128).
// (XCD swizzle tried round 3: regressed, keep natural bn-fastest order.)

__global__ __launch_bounds__(512) void gemm_qkv(const bf16* __restrict__ A,
                                                const bf16* __restrict__ Bt,
                                                unsigned short* __restrict__ outQ,
                                                unsigned short* __restrict__ outK,
                                                unsigned short* __restrict__ outV,
                                                float qscale) {
    const int KD = 1024;
    __shared__ __align__(16) char smem[49152];
    bf16* sA = (bf16*)smem;            // [256][64] swizzled
    bf16* sB = (bf16*)(smem + 32768);  // [128][64] swizzled
    const int t = threadIdx.x;
    const int w = t >> 6, lane = t & 63, l15 = lane & 15, qd = lane >> 4;
    const int bn = blockIdx.x, bm = blockIdx.y;
    const int wm = (w >> 1) * 64, wn = (w & 1) * 64;
    const int sw = l15 & 7;

    f32x4 acc[4][4];
#pragma unroll
    for (int i = 0; i < 4; i++)
#pragma unroll
        for (int j = 0; j < 4; j++) acc[i][j] = (f32x4){0.f, 0.f, 0.f, 0.f};

    // staging: wave w covers A rows w*32..w*32+31 (4 async16/thread) and
    // B rows w*16..w*16+15 (2 async16/thread); row&7 == rsub preserved.
    const int rsub = lane >> 3;
    const int csrc = ((lane & 7) ^ rsub) << 3;
    const bf16* Ab = A + (size_t)(bm * 256 + w * 32 + rsub) * KD + csrc;
    const bf16* Bb = Bt + (size_t)(bn * 128 + w * 16 + rsub) * KD + csrc;
    bf16* sAw = sA + (w * 32) * 64;
    bf16* sBw = sB + (w * 16) * 64;

    for (int kt = 0; kt < 16; ++kt) {
#pragma unroll
        for (int j = 0; j < 4; ++j)
            async16(Ab + (size_t)(j * 8) * KD + kt * 64, sAw + j * 512);
#pragma unroll
        for (int j = 0; j < 2; ++j)
            async16(Bb + (size_t)(j * 8) * KD + kt * 64, sBw + j * 512);
        __syncthreads();
#pragma unroll
        for (int ks = 0; ks < 2; ++ks) {
            const int cphys = (((ks * 4 + qd) ^ sw) << 3);
            short8 af[4], bfv[4];
#pragma unroll
            for (int mi = 0; mi < 4; mi++)
                af[mi] = *(const short8*)&sA[(wm + mi * 16 + l15) * 64 + cphys];
#pragma unroll
            for (int ni = 0; ni < 4; ni++)
                bfv[ni] = *(const short8*)&sB[(wn + ni * 16 + l15) * 64 + cphys];
#pragma unroll
            for (int mi = 0; mi < 4; mi++)
#pragma unroll
                for (int ni = 0; ni < 4; ni++)
                    acc[mi][ni] = __builtin_amdgcn_mfma_f32_16x16x32_bf16(af[mi], bfv[ni],
                                                                          acc[mi][ni], 0, 0, 0);
        }
        __syncthreads();
    }

    unsigned short* sC = (unsigned short*)smem;
    const int part = bn >> 3;  // block-uniform: 0=Q 1=K 2=V
    const int hb = (bn & 7) * 2;
    if (part < 2) {
        const float sc = (part == 0) ? qscale : 1.0f;
        unsigned short* dst = (part == 0) ? outQ : outK;
#pragma unroll
        for (int pass = 0; pass < 2; ++pass) {
            if (pass) __syncthreads();
            if ((wm >> 7) == pass) {
#pragma unroll
                for (int mi = 0; mi < 4; mi++)
#pragma unroll
                    for (int ni = 0; ni < 4; ni++)
#pragma unroll
                        for (int r = 0; r < 4; r++)
                            sC[((wm & 127) + mi * 16 + qd * 4 + r) * 136 + wn + ni * 16 +
                               l15] = f2bf(acc[mi][ni][r] * sc);
            }
            __syncthreads();
#pragma unroll
            for (int i = 0; i < 4; i++) {
                const int j = t + i * 512;
                const int row = j >> 4, c16 = j & 15;
                uint4 v = *(const uint4*)&sC[row * 136 + c16 * 8];
                const int m = bm * 256 + pass * 128 + row;
                const int b = m >> 11, ns = m & 2047;
                const int h = hb + (c16 >> 3);
                const int dd = (c16 & 7) * 8;
                *(uint4*)&dst[((size_t)(b * 16 + h) * 2048 + ns) * 64 + dd] = v;
            }
        }
    } else {
        // V: stage TRANSPOSED [feature][token-half], store to [B,H,D,N]
        const int m0b = bm * 256;
        const int b = m0b >> 11, ns0 = m0b & 2047;
#pragma unroll
        for (int pass = 0; pass < 2; ++pass) {
            if (pass) __syncthreads();
            if ((wm >> 7) == pass) {
#pragma unroll
                for (int ni = 0; ni < 4; ni++)
#pragma unroll
                    for (int mi = 0; mi < 4; mi++) {
                        uint2 pk;
                        pk.x = (unsigned)f2bf(acc[mi][ni][0]) |
                               ((unsigned)f2bf(acc[mi][ni][1]) << 16);
                        pk.y = (unsigned)f2bf(acc[mi][ni][2]) |
                               ((unsigned)f2bf(acc[mi][ni][3]) << 16);
                        *(uint2*)&sC[(wn + ni * 16 + l15) * 136 + (wm & 127) + mi * 16 +
                                     qd * 4] = pk;
                    }
            }
            __syncthreads();
#pragma unroll
            for (int i = 0; i < 4; i++) {
                const int j = t + i * 512;
                const int f = j >> 4, tc = j & 15;
                uint4 v = *(const uint4*)&sC[f * 136 + tc * 8];
                const int h = hb + (f >> 6), dd = f & 63;
                *(uint4*)&outV[((size_t)(b * 16 + h) * 64 + dd) * 2048 + ns0 + pass * 128 +
                               tc * 8] = v;
            }
        }
    }
}

// ---------------- out-projection GEMM: 128x128 tile (unchanged, verified) ----------------

__global__ __launch_bounds__(256) void gemm_out(const bf16* __restrict__ A,
                                                const bf16* __restrict__ Bt,
                                                float* __restrict__ outF) {
    const int KD = 1024;
    __shared__ __align__(16) char smem[34816];
    bf16* sA = (bf16*)smem;            // [128][64] swizzled
    bf16* sB = (bf16*)(smem + 16384);  // [128][64] swizzled
    const int t = threadIdx.x;
    const int w = t >> 6, lane = t & 63, l15 = lane & 15, qd = lane >> 4;
    const int bn = blockIdx.x, bm = blockIdx.y;
    const int wm = (w >> 1) * 64, wn = (w & 1) * 64;
    const int sw = l15 & 7;

    f32x4 acc[4][4];
#pragma unroll
    for (int i = 0; i < 4; i++)
#pragma unroll
        for (int j = 0; j < 4; j++) acc[i][j] = (f32x4){0.f, 0.f, 0.f, 0.f};

    const int rsub = lane >> 3;
    const int csrc = ((lane & 7) ^ rsub) << 3;
    const bf16* Ab = A + (size_t)(bm * 128 + w * 32 + rsub) * KD + csrc;
    const bf16* Bb = Bt + (size_t)(bn * 128 + w * 32 + rsub) * KD + csrc;
    bf16* sAw = sA + (w * 32) * 64;
    bf16* sBw = sB + (w * 32) * 64;

    for (int kt = 0; kt < 16; ++kt) {
#pragma unroll
        for (int j = 0; j < 4; ++j) {
            async16(Ab + (size_t)(j * 8) * KD + kt * 64, sAw + j * 512);
            async16(Bb + (size_t)(j * 8) * KD + kt * 64, sBw + j * 512);
        }
        __syncthreads();
#pragma unroll
        for (int ks = 0; ks < 2; ++ks) {
            const int cphys = (((ks * 4 + qd) ^ sw) << 3);
            short8 af[4], bfv[4];
#pragma unroll
            for (int mi = 0; mi < 4; mi++)
                af[mi] = *(const short8*)&sA[(wm + mi * 16 + l15) * 64 + cphys];
#pragma unroll
            for (int ni = 0; ni < 4; ni++)
                bfv[ni] = *(const short8*)&sB[(wn + ni * 16 + l15) * 64 + cphys];
#pragma unroll
            for (int mi = 0; mi < 4; mi++)
#pragma unroll
                for (int ni = 0; ni < 4; ni++)
                    acc[mi][ni] = __builtin_amdgcn_mfma_f32_16x16x32_bf16(af[mi], bfv[ni],
                                                                          acc[mi][ni], 0, 0, 0);
        }
        __syncthreads();
    }

    float* sF = (float*)smem;
#pragma unroll
    for (int pass = 0; pass < 2; ++pass) {
        if (pass) __syncthreads();
        if ((wm >> 6) == pass) {
#pragma unroll
            for (int mi = 0; mi < 4; mi++)
#pragma unroll
                for (int ni = 0; ni < 4; ni++)
#pragma unroll
                    for (int r = 0; r < 4; r++)
                        sF[(mi * 16 + qd * 4 + r) * 132 + wn + ni * 16 + l15] =
                            acc[mi][ni][r];
        }
        __syncthreads();
#pragma unroll
        for (int i = 0; i < 8; i++) {
            const int j = t + i * 256;
            const int row = j >> 5, c4 = j & 31;
            float4 v = *(const float4*)&sF[row * 132 + c4 * 4];
            *(float4*)&outF[(size_t)(bm * 128 + pass * 64 + row) * 1024 + bn * 128 + c4 * 4] =
                v;
        }
    }
}

// ---------------- flash attention, 32x32x16 MFMA, ZERO-repack PV ----------------
// (round-8 kernel, unchanged: 512 thr = 8 waves, 256 q rows/block, one 32-row
// q-group per wave; 64-key double-buffered staging, issue-early / wait-late.)
// ATTN IS CLOSED (rounds 1-8): pinned ~100-102 µs across 5 structural variants;
// VALU floor (~35 µs, 72% irreducible exp2) + MFMA floor (~28 µs) + imperfect
// overlap. Piecewise pipeline grafts all regressed (r5 −10%, r6 −18%, r7 −20%);
// keep VGPR <= 128, keep the 2-buffer __syncthreads loop.
// S^T C-layout: col=lane&31=q, key=(reg&3)+8*(reg>>2)+4*hl. The packed exp2
// pairs are fed DIRECTLY as the PV B-operand; MFMA k-order is permutation-
// invariant, so the V^T A-fragment is read in the SAME permuted key order.

__global__ __launch_bounds__(512) void attn_kernel(const bf16* __restrict__ Q,
                                                   const bf16* __restrict__ K,
                                                   const bf16* __restrict__ Vt,
                                                   bf16* __restrict__ Y) {
    const int blk = blockIdx.x;                  // 512 blocks
    const int bh = (blk & 7) * 8 + (blk >> 6);   // XCD-swizzle: 8 bh per XCD
    const int qt = (blk >> 3) & 7;               // 8 q-tiles of 256 rows
    const int b = bh >> 4, h16 = bh & 15;
    const int t = threadIdx.x, w = t >> 6, lane = t & 63;  // w in 0..7
    const int c = lane & 31, hl = lane >> 5;
    const int sw = c & 7;

    __shared__ __align__(16) char smem[36864];
    bf16* sK0 = (bf16*)smem;              // [64][64] xor-swizzled (rows=key, cols=d)
    bf16* sK1 = (bf16*)(smem + 8192);
    bf16* sV0 = (bf16*)(smem + 16384);    // [64][64] xor-swizzled (rows=d, cols=key)
    bf16* sV1 = (bf16*)(smem + 24576);
    bf16* sO = (bf16*)smem;               // epilogue overlay [256][72]

    const size_t bhbase = (size_t)bh * 2048 * 64;

    short8 qf[4];
#pragma unroll
    for (int kc = 0; kc < 4; kc++)
        qf[kc] = *(const short8*)(Q + bhbase + (size_t)(qt * 256 + w * 32 + c) * 64 +
                                  kc * 16 + hl * 8);

    f32x16 z16;
#pragma unroll
    for (int i = 0; i < 16; i++) z16[i] = 0.f;
    f32x16 ot[2];
#pragma unroll
    for (int i = 0; i < 16; i++) { ot[0][i] = 0.f; ot[1][i] = 0.f; }
    float l_run = 0.f;

    const int rsub = lane >> 3;
    const int cg = ((lane & 7) ^ rsub) << 3;
    const bf16* Kb = K + bhbase + (size_t)(w * 8 + rsub) * 64 + cg;    // keys, d-major rows
    const bf16* Vb = Vt + bhbase + (size_t)(w * 8 + rsub) * 2048 + cg; // d rows, key-major
    const int ldsoff = w * 512;  // elements: w*1024 bytes

#define STAGE(ktile, sKb, sVb)                                   \
    {                                                            \
        async16(Kb + (size_t)(ktile) * 4096, (sKb) + ldsoff);    \
        async16(Vb + (size_t)(ktile) * 64,   (sVb) + ldsoff);    \
    }

    auto compute = [&](const bf16* __restrict__ sKb, const bf16* __restrict__ sVb) {
#pragma unroll
        for (int kt2 = 0; kt2 < 2; ++kt2) {
            short8 kf0 = *(const short8*)&sKb[(kt2 * 32 + c) * 64 + ((hl ^ sw) << 3)];
            __builtin_amdgcn_s_setprio(1);
            f32x16 accS = __builtin_amdgcn_mfma_f32_32x32x16_bf16(kf0, qf[0], z16, 0, 0, 0);
#pragma unroll
            for (int kc = 1; kc < 4; kc++) {
                short8 kf =
                    *(const short8*)&sKb[(kt2 * 32 + c) * 64 + (((kc * 2 + hl) ^ sw) << 3)];
                accS = __builtin_amdgcn_mfma_f32_32x32x16_bf16(kf, qf[kc], accS, 0, 0, 0);
            }
            __builtin_amdgcn_s_setprio(0);
            unsigned u[8];
            float ls = 0.f;
#pragma unroll
            for (int i = 0; i < 8; i++) {
                float p0 = fast_exp2(accS[2 * i]);
                float p1 = fast_exp2(accS[2 * i + 1]);
                ls += p0 + p1;
                u[i] = pkbf(p0, p1);
            }
            l_run += ls;
            union { uint4 u4; short8 s8; } F[2];
            F[0].u4.x = u[0]; F[0].u4.y = u[1]; F[0].u4.z = u[2]; F[0].u4.w = u[3];
            F[1].u4.x = u[4]; F[1].u4.y = u[5]; F[1].u4.z = u[6]; F[1].u4.w = u[7];
            __builtin_amdgcn_s_setprio(1);
#pragma unroll
            for (int g = 0; g < 2; ++g) {
#pragma unroll
                for (int mi2 = 0; mi2 < 2; mi2++) {
                    const bf16* vr = &sVb[(mi2 * 32 + c) * 64];
                    uint2 a0 = *(const uint2*)&vr[(((kt2 * 4 + 2 * g) ^ sw) << 3) + hl * 4];
                    uint2 a1 =
                        *(const uint2*)&vr[(((kt2 * 4 + 2 * g + 1) ^ sw) << 3) + hl * 4];
                    union { uint4 u4; short8 s8; } vf;
                    vf.u4.x = a0.x; vf.u4.y = a0.y; vf.u4.z = a1.x; vf.u4.w = a1.y;
                    ot[mi2] =
                        __builtin_amdgcn_mfma_f32_32x32x16_bf16(vf.s8, F[g].s8, ot[mi2], 0, 0, 0);
                }
            }
            __builtin_amdgcn_s_setprio(0);
        }
    };

    STAGE(0, sK0, sV0);
    for (int kt = 0; kt < 32; kt += 2) {
        __syncthreads();
        STAGE(kt + 1, sK1, sV1);
        compute(sK0, sV0);
        __syncthreads();
        if (kt + 2 < 32) STAGE(kt + 2, sK0, sV0);
        compute(sK1, sV1);
    }
    __syncthreads();

    float l = l_run + __shfl_xor(l_run, 32, 64);
    float rl = 1.f / l;
#pragma unroll
    for (int mi2 = 0; mi2 < 2; mi2++)
#pragma unroll
        for (int q4 = 0; q4 < 4; q4++) {
            const int d0 = mi2 * 32 + q4 * 8 + hl * 4;
            uint2 pk;
            pk.x = pkbf(ot[mi2][q4 * 4 + 0] * rl, ot[mi2][q4 * 4 + 1] * rl);
            pk.y = pkbf(ot[mi2][q4 * 4 + 2] * rl, ot[mi2][q4 * 4 + 3] * rl);
            *(uint2*)&sO[(w * 32 + c) * 72 + d0] = pk;
        }
    __syncthreads();
#pragma unroll
    for (int i = 0; i < 4; i++) {
        int row = (t >> 3) + i * 64, doff = (t & 7) * 8;
        uint4 vv = *(const uint4*)&sO[row * 72 + doff];
        *(uint4*)(Y + ((size_t)(b * 2048 + qt * 256 + row)) * 1024 + h16 * 64 + doff) = vv;
    }
#undef STAGE
}

// ---------------- launch ----------------

extern "C" void kernel_launch(void* const* d_in, const int* in_sizes, int n_in,
                              void* d_out, int out_size, void* d_ws, size_t ws_size,
                              hipStream_t stream) {
    const float* x = (const float*)d_in[0];
    const float* w_attn = (const float*)d_in[1];
    const float* w_proj = (const float*)d_in[2];
    float* out = (float*)d_out;
    char* ws = (char*)d_ws;

    bf16* xb = (bf16*)(ws);                    // 16 MiB; reused as Y after attention
    bf16* waT = (bf16*)(ws + 16777216);        // 6 MiB
    bf16* wpT = (bf16*)(ws + 23068672);        // 2 MiB
    bf16* qb = (bf16*)(ws + 25165824);         // 16 MiB
    bf16* kb = (bf16*)(ws + 41943040);         // 16 MiB
    bf16* vtb = (bf16*)(ws + 58720256);        // 16 MiB, transposed [B,H,D,N]

    prep_fused<<<12288, 256, 0, stream>>>(x, (unsigned short*)xb, w_attn,
                                          (unsigned short*)waT, w_proj,
                                          (unsigned short*)wpT);

    const float qscale = 0.125f * 1.44269504088896340736f;  // 1/sqrt(D) * log2(e)
    gemm_qkv<<<dim3(24, 32), 512, 0, stream>>>(xb, waT, (unsigned short*)qb,
                                               (unsigned short*)kb, (unsigned short*)vtb,
                                               qscale);
    attn_kernel<<<dim3(512), 512, 0, stream>>>(qb, kb, vtb, xb /* Y reuses xb */);
    gemm_out<<<dim3(8, 64), 256, 0, stream>>>(xb, wpT, out);
}

// Round 10
// 268.688 us; speedup vs baseline: 1.0216x; 1.0216x over previous
//
#include <hip/hip_runtime.h>
#include <hip/hip_bf16.h>

typedef __hip_bfloat16 bf16;
typedef short short8 __attribute__((ext_vector_type(8)));
typedef float f32x4 __attribute__((ext_vector_type(4)));
typedef float f32x16 __attribute__((ext_vector_type(16)));

#define GLOBAL_AS __attribute__((address_space(1)))
#define LDS_AS __attribute__((address_space(3)))

__device__ inline unsigned short f2bf(float x) {
    union { float f; unsigned u; } v; v.f = x;
    unsigned r = v.u + 0x7fffu + ((v.u >> 16) & 1u);
    return (unsigned short)(r >> 16);
}

__device__ inline unsigned pkbf(float a, float b) {
    float2 f; f.x = a; f.y = b;
    union { __hip_bfloat162 h; unsigned u; } c;
    c.h = __float22bfloat162_rn(f);
    return c.u;
}

__device__ inline float fast_exp2(float x) {
#if __has_builtin(__builtin_amdgcn_exp2f)
    return __builtin_amdgcn_exp2f(x);
#else
    return exp2f(x);
#endif
}

// async global->LDS, 16 B per lane; LDS dest = wave-uniform base + lane*16
__device__ inline void async16(const void* g, void* l) {
    __builtin_amdgcn_global_load_lds((const GLOBAL_AS void*)g, (LDS_AS void*)l, 16, 0, 0);
}

// ---------------- prep kernels ----------------
// (separate launches measured FASTER than a fused branch kernel — round 9:
// fusion + 256x128 gemm tile bundle regressed ~5 µs; keep the 3-launch form.)

__global__ __launch_bounds__(256) void cvt_f32_bf16(const float* __restrict__ in,
                                                    unsigned short* __restrict__ out, int n4) {
    int i = blockIdx.x * 256 + threadIdx.x;
    if (i < n4) {
        float4 v = ((const float4*)in)[i];
        ushort4 o;
        o.x = f2bf(v.x); o.y = f2bf(v.y); o.z = f2bf(v.z); o.w = f2bf(v.w);
        ((ushort4*)out)[i] = o;
    }
}

// in: [R][Cc] f32 row-major  ->  out: [Cc][R] bf16 row-major
__global__ __launch_bounds__(256) void transpose_bf16(const float* __restrict__ in,
                                                      unsigned short* __restrict__ out,
                                                      int R, int Cc) {
    __shared__ float s[32][33];
    int tx = threadIdx.x & 31, ty = threadIdx.x >> 5;
    int c0 = blockIdx.x * 32, r0 = blockIdx.y * 32;
#pragma unroll
    for (int i = 0; i < 4; i++)
        s[ty + i * 8][tx] = in[(size_t)(r0 + ty + i * 8) * Cc + c0 + tx];
    __syncthreads();
#pragma unroll
    for (int i = 0; i < 4; i++)
        out[(size_t)(c0 + ty + i * 8) * R + r0 + tx] = f2bf(s[tx][ty + i * 8]);
}

// ---------------- GEMM: C[m][n] = sum_k A[m][k] * Bt[n][k], K=1024 ----------------
// MODE 0: Q/K -> [B,H,N,D] bf16 (Q scaled), V -> TRANSPOSED [B,H,D,N] bf16.
// MODE 1: fp32 out.
// SETTLED (rounds 3/9): 128x128 tile + natural bn-fastest block order is the
// structure-optimum here. XCD chunk swizzle: −9 µs (r3). 256x128/512-thr tile:
// −5 µs bundled (r9). Do not revisit.

template <int MODE>
__global__ __launch_bounds__(256) void gemm_bf16(const bf16* __restrict__ A,
                                                 const bf16* __restrict__ Bt,
                                                 unsigned short* __restrict__ outQ,
                                                 unsigned short* __restrict__ outK,
                                                 unsigned short* __restrict__ outV,
                                                 float* __restrict__ outF, float qscale) {
    const int KD = 1024;
    __shared__ __align__(16) char smem[34816];
    bf16* sA = (bf16*)smem;            // [128][64] swizzled
    bf16* sB = (bf16*)(smem + 16384);  // [128][64] swizzled
    const int t = threadIdx.x;
    const int w = t >> 6, lane = t & 63, l15 = lane & 15, qd = lane >> 4;
    const int bn = blockIdx.x, bm = blockIdx.y;
    const int wm = (w >> 1) * 64, wn = (w & 1) * 64;
    const int sw = l15 & 7;

    f32x4 acc[4][4];
#pragma unroll
    for (int i = 0; i < 4; i++)
#pragma unroll
        for (int j = 0; j < 4; j++) acc[i][j] = (f32x4){0.f, 0.f, 0.f, 0.f};

    const int rsub = lane >> 3;
    const int csrc = ((lane & 7) ^ rsub) << 3;
    const bf16* Ab = A + (size_t)(bm * 128 + w * 32 + rsub) * KD + csrc;
    const bf16* Bb = Bt + (size_t)(bn * 128 + w * 32 + rsub) * KD + csrc;
    bf16* sAw = sA + (w * 32) * 64;
    bf16* sBw = sB + (w * 32) * 64;

    for (int kt = 0; kt < 16; ++kt) {
#pragma unroll
        for (int j = 0; j < 4; ++j) {
            async16(Ab + (size_t)(j * 8) * KD + kt * 64, sAw + j * 512);
            async16(Bb + (size_t)(j * 8) * KD + kt * 64, sBw + j * 512);
        }
        __syncthreads();
#pragma unroll
        for (int ks = 0; ks < 2; ++ks) {
            const int cphys = (((ks * 4 + qd) ^ sw) << 3);
            short8 af[4], bfv[4];
#pragma unroll
            for (int mi = 0; mi < 4; mi++)
                af[mi] = *(const short8*)&sA[(wm + mi * 16 + l15) * 64 + cphys];
#pragma unroll
            for (int ni = 0; ni < 4; ni++)
                bfv[ni] = *(const short8*)&sB[(wn + ni * 16 + l15) * 64 + cphys];
#pragma unroll
            for (int mi = 0; mi < 4; mi++)
#pragma unroll
                for (int ni = 0; ni < 4; ni++)
                    acc[mi][ni] = __builtin_amdgcn_mfma_f32_16x16x32_bf16(af[mi], bfv[ni],
                                                                          acc[mi][ni], 0, 0, 0);
        }
        __syncthreads();
    }

    if (MODE == 0) {
        unsigned short* sC = (unsigned short*)smem;
        const int part = bn >> 3;  // block-uniform: 0=Q 1=K 2=V
        const int hb = (bn & 7) * 2;
        if (part < 2) {
            const float sc = (part == 0) ? qscale : 1.0f;
            unsigned short* dst = (part == 0) ? outQ : outK;
#pragma unroll
            for (int mi = 0; mi < 4; mi++)
#pragma unroll
                for (int ni = 0; ni < 4; ni++)
#pragma unroll
                    for (int r = 0; r < 4; r++)
                        sC[(wm + mi * 16 + qd * 4 + r) * 136 + wn + ni * 16 + l15] =
                            f2bf(acc[mi][ni][r] * sc);
            __syncthreads();
#pragma unroll
            for (int i = 0; i < 8; i++) {
                const int j = t + i * 256;
                const int row = j >> 4, c16 = j & 15;
                uint4 v = *(const uint4*)&sC[row * 136 + c16 * 8];
                const int m = bm * 128 + row;
                const int b = m >> 11, ns = m & 2047;
                const int h = hb + (c16 >> 3);
                const int dd = (c16 & 7) * 8;
                *(uint4*)&dst[((size_t)(b * 16 + h) * 2048 + ns) * 64 + dd] = v;
            }
        } else {
            // V: stage TRANSPOSED [feature][token], store to [B,H,D,N]
#pragma unroll
            for (int ni = 0; ni < 4; ni++)
#pragma unroll
                for (int mi = 0; mi < 4; mi++) {
                    uint2 pk;
                    pk.x = (unsigned)f2bf(acc[mi][ni][0]) | ((unsigned)f2bf(acc[mi][ni][1]) << 16);
                    pk.y = (unsigned)f2bf(acc[mi][ni][2]) | ((unsigned)f2bf(acc[mi][ni][3]) << 16);
                    *(uint2*)&sC[(wn + ni * 16 + l15) * 136 + wm + mi * 16 + qd * 4] = pk;
                }
            __syncthreads();
            const int m0b = bm * 128;
            const int b = m0b >> 11, ns0 = m0b & 2047;
#pragma unroll
            for (int i = 0; i < 8; i++) {
                const int j = t + i * 256;
                const int f = j >> 4, tc = j & 15;
                uint4 v = *(const uint4*)&sC[f * 136 + tc * 8];
                const int h = hb + (f >> 6), dd = f & 63;
                *(uint4*)&outV[((size_t)(b * 16 + h) * 64 + dd) * 2048 + ns0 + tc * 8] = v;
            }
        }
    } else {
        float* sF = (float*)smem;
#pragma unroll
        for (int pass = 0; pass < 2; ++pass) {
            if (pass) __syncthreads();
            if ((wm >> 6) == pass) {
#pragma unroll
                for (int mi = 0; mi < 4; mi++)
#pragma unroll
                    for (int ni = 0; ni < 4; ni++)
#pragma unroll
                        for (int r = 0; r < 4; r++)
                            sF[(mi * 16 + qd * 4 + r) * 132 + wn + ni * 16 + l15] =
                                acc[mi][ni][r];
            }
            __syncthreads();
#pragma unroll
            for (int i = 0; i < 8; i++) {
                const int j = t + i * 256;
                const int row = j >> 5, c4 = j & 31;
                float4 v = *(const float4*)&sF[row * 132 + c4 * 4];
                *(float4*)&outF[(size_t)(bm * 128 + pass * 64 + row) * 1024 + bn * 128 +
                                c4 * 4] = v;
            }
        }
    }
}

// ---------------- flash attention, 32x32x16 MFMA, ZERO-repack PV ----------------
// Q,K: [B*H, 2048, 64] bf16 (Q pre-scaled by 0.125*log2e); Vt: [B*H, 64, 2048] bf16.
// Y: [B, N, H*D] bf16. 256 thr; 256 q rows/block (64/wave = TWO 32-row q-groups);
// 64-key double-buffered staging tiles (4 x 8KB LDS, issue-early / wait-late).
// THIS IS THE SESSION OPTIMUM (round 4, 100.5 µs attn / 270.0 µs total).
// Each wave processes TWO q-column-groups (qA = w*64+c, qB = qA+32): every K/V
// fragment read feeds 2 MFMAs -> LDS bytes and bank-conflict cycles per FLOP
// halved vs the 1-group form.
// CLOSED DIRECTIONS (measured, do not revisit):
//  r5 hand-pipelined S/exp2/PV phases: −10% (VGPR 148, occupancy cliff).
//  r6 4-ring counted-vmcnt: −18% (VGPR 180, 4x code bloat).
//  r7 ones-MFMA l-accum: −20% (matrix pipe +25%, VGPR 140).
//  r8 512-thr shared staging: neutral (101.7).
//  HARD RULE: VGPR <= 128; keep the 2-buffer __syncthreads loop.
//  r2 fragment-order LDS staging: FAILED correctness; do not touch LDS layout
//  or gemm-side V placement.
// S^T C-layout: col=lane&31=q, key=(reg&3)+8*(reg>>2)+4*hl. The packed exp2
// pairs are fed DIRECTLY as the PV B-operand; MFMA k-order is permutation-
// invariant, so the V^T A-fragment is read in the SAME permuted key order.
// NOTE: plain __launch_bounds__(256) — a (256,4) min-waves bound clamps the
// unified register budget to 64 and spills accumulators to scratch. Do not re-add.

__global__ __launch_bounds__(256) void attn_kernel(const bf16* __restrict__ Q,
                                                   const bf16* __restrict__ K,
                                                   const bf16* __restrict__ Vt,
                                                   bf16* __restrict__ Y) {
    const int blk = blockIdx.x;                  // 512 blocks
    const int bh = (blk & 7) * 8 + (blk >> 6);   // XCD-swizzle: 8 bh per XCD
    const int qt = (blk >> 3) & 7;               // 8 q-tiles of 256 rows
    const int b = bh >> 4, h16 = bh & 15;
    const int t = threadIdx.x, w = t >> 6, lane = t & 63;
    const int c = lane & 31, hl = lane >> 5;
    const int sw = c & 7;

    __shared__ __align__(16) char smem[36864];
    bf16* sK0 = (bf16*)smem;              // [64][64] xor-swizzled (rows=key, cols=d)
    bf16* sK1 = (bf16*)(smem + 8192);
    bf16* sV0 = (bf16*)(smem + 16384);    // [64][64] xor-swizzled (rows=d, cols=key)
    bf16* sV1 = (bf16*)(smem + 24576);
    bf16* sO = (bf16*)smem;               // epilogue overlay [256][72]

    const size_t bhbase = (size_t)bh * 2048 * 64;

    // Q B-frags for both q-groups: qA = qt*256 + w*64 + c, qB = qA + 32;
    // d = kc*16 + hl*8 + j
    short8 qfA[4], qfB[4];
#pragma unroll
    for (int kc = 0; kc < 4; kc++) {
        qfA[kc] = *(const short8*)(Q + bhbase + (size_t)(qt * 256 + w * 64 + c) * 64 +
                                   kc * 16 + hl * 8);
        qfB[kc] = *(const short8*)(Q + bhbase + (size_t)(qt * 256 + w * 64 + 32 + c) * 64 +
                                   kc * 16 + hl * 8);
    }

    f32x16 z16;
#pragma unroll
    for (int i = 0; i < 16; i++) z16[i] = 0.f;
    f32x16 ot[4];  // [0..1]=group A (mi2 0,1), [2..3]=group B
#pragma unroll
    for (int j = 0; j < 4; j++)
#pragma unroll
        for (int i = 0; i < 16; i++) ot[j][i] = 0.f;
    float lA = 0.f, lB = 0.f;

    // staging addressing (identical to verified round-1 kernel)
    const int rsub = lane >> 3;
    const int cg = ((lane & 7) ^ rsub) << 3;
    const bf16* Kb = K + bhbase + (size_t)(w * 16 + rsub) * 64 + cg;    // keys, d-major rows
    const bf16* Vb = Vt + bhbase + (size_t)(w * 16 + rsub) * 2048 + cg; // d rows, key-major
    const int ldsoff = (w * 16) * 64;

#define STAGE(ktile, sKb, sVb)                                                      \
    {                                                                               \
        _Pragma("unroll") for (int j = 0; j < 2; j++) {                             \
            async16(Kb + (size_t)(ktile) * 4096 + j * 512, (sKb) + ldsoff + j * 512); \
            async16(Vb + (size_t)(ktile) * 64 + (size_t)j * 16384,                  \
                    (sVb) + ldsoff + j * 512);                                      \
        }                                                                           \
    }

    auto compute = [&](const bf16* __restrict__ sKb, const bf16* __restrict__ sVb) {
#pragma unroll
        for (int kt2 = 0; kt2 < 2; ++kt2) {
            // K fragments (shared by both q-groups), then S^T = K * Q^T
            short8 kf[4];
#pragma unroll
            for (int kc = 0; kc < 4; kc++)
                kf[kc] =
                    *(const short8*)&sKb[(kt2 * 32 + c) * 64 + (((kc * 2 + hl) ^ sw) << 3)];
            __builtin_amdgcn_s_setprio(1);
            f32x16 accA = __builtin_amdgcn_mfma_f32_32x32x16_bf16(kf[0], qfA[0], z16, 0, 0, 0);
            f32x16 accB = __builtin_amdgcn_mfma_f32_32x32x16_bf16(kf[0], qfB[0], z16, 0, 0, 0);
#pragma unroll
            for (int kc = 1; kc < 4; kc++) {
                accA = __builtin_amdgcn_mfma_f32_32x32x16_bf16(kf[kc], qfA[kc], accA, 0, 0, 0);
                accB = __builtin_amdgcn_mfma_f32_32x32x16_bf16(kf[kc], qfB[kc], accB, 0, 0, 0);
            }
            __builtin_amdgcn_s_setprio(0);
            // P = exp2(S) for both groups; natural pack, fed directly as B-operand.
            unsigned uA[8], uB[8];
            float lsA = 0.f, lsB = 0.f;
#pragma unroll
            for (int i = 0; i < 8; i++) {
                float a0 = fast_exp2(accA[2 * i]);
                float a1 = fast_exp2(accA[2 * i + 1]);
                lsA += a0 + a1;
                uA[i] = pkbf(a0, a1);
                float b0 = fast_exp2(accB[2 * i]);
                float b1 = fast_exp2(accB[2 * i + 1]);
                lsB += b0 + b1;
                uB[i] = pkbf(b0, b1);
            }
            lA += lsA;
            lB += lsB;
            union { uint4 u4; short8 s8; } FA[2], FB[2];
            FA[0].u4.x = uA[0]; FA[0].u4.y = uA[1]; FA[0].u4.z = uA[2]; FA[0].u4.w = uA[3];
            FA[1].u4.x = uA[4]; FA[1].u4.y = uA[5]; FA[1].u4.z = uA[6]; FA[1].u4.w = uA[7];
            FB[0].u4.x = uB[0]; FB[0].u4.y = uB[1]; FB[0].u4.z = uB[2]; FB[0].u4.w = uB[3];
            FB[1].u4.x = uB[4]; FB[1].u4.y = uB[5]; FB[1].u4.z = uB[6]; FB[1].u4.w = uB[7];
            // O^T += V^T * P^T ; each V fragment feeds BOTH q-groups.
            __builtin_amdgcn_s_setprio(1);
#pragma unroll
            for (int g = 0; g < 2; ++g) {
#pragma unroll
                for (int mi2 = 0; mi2 < 2; mi2++) {
                    const bf16* vr = &sVb[(mi2 * 32 + c) * 64];
                    uint2 a0 = *(const uint2*)&vr[(((kt2 * 4 + 2 * g) ^ sw) << 3) + hl * 4];
                    uint2 a1 =
                        *(const uint2*)&vr[(((kt2 * 4 + 2 * g + 1) ^ sw) << 3) + hl * 4];
                    union { uint4 u4; short8 s8; } vf;
                    vf.u4.x = a0.x; vf.u4.y = a0.y; vf.u4.z = a1.x; vf.u4.w = a1.y;
                    ot[mi2] =
                        __builtin_amdgcn_mfma_f32_32x32x16_bf16(vf.s8, FA[g].s8, ot[mi2], 0, 0, 0);
                    ot[2 + mi2] = __builtin_amdgcn_mfma_f32_32x32x16_bf16(vf.s8, FB[g].s8,
                                                                          ot[2 + mi2], 0, 0, 0);
                }
            }
            __builtin_amdgcn_s_setprio(0);
        }
    };

    // double-buffered main loop: 32 tiles of 64 keys, issue-early / wait-late.
    STAGE(0, sK0, sV0);
    for (int kt = 0; kt < 32; kt += 2) {
        __syncthreads();                     // drains tile kt loads (issued 1 body ago)
        STAGE(kt + 1, sK1, sV1);             // issue next tile, no wait
        compute(sK0, sV0);
        __syncthreads();                     // drains tile kt+1 loads
        if (kt + 2 < 32) STAGE(kt + 2, sK0, sV0);
        compute(sK1, sV1);
    }
    __syncthreads();  // all waves done reading K/V buffers before sO overlay

    // epilogue: l reduce (single xor-32 per group), normalize, transpose via LDS,
    // coalesced store of 256 rows.
    float lAt = lA + __shfl_xor(lA, 32, 64);
    float lBt = lB + __shfl_xor(lB, 32, 64);
    float rlA = 1.f / lAt;
    float rlB = 1.f / lBt;
#pragma unroll
    for (int mi2 = 0; mi2 < 2; mi2++)
#pragma unroll
        for (int q4 = 0; q4 < 4; q4++) {
            const int d0 = mi2 * 32 + q4 * 8 + hl * 4;
            uint2 pkA;
            pkA.x = pkbf(ot[mi2][q4 * 4 + 0] * rlA, ot[mi2][q4 * 4 + 1] * rlA);
            pkA.y = pkbf(ot[mi2][q4 * 4 + 2] * rlA, ot[mi2][q4 * 4 + 3] * rlA);
            *(uint2*)&sO[(w * 64 + c) * 72 + d0] = pkA;
            uint2 pkB;
            pkB.x = pkbf(ot[2 + mi2][q4 * 4 + 0] * rlB, ot[2 + mi2][q4 * 4 + 1] * rlB);
            pkB.y = pkbf(ot[2 + mi2][q4 * 4 + 2] * rlB, ot[2 + mi2][q4 * 4 + 3] * rlB);
            *(uint2*)&sO[(w * 64 + 32 + c) * 72 + d0] = pkB;
        }
    __syncthreads();
#pragma unroll
    for (int i = 0; i < 8; i++) {
        int row = (t >> 3) + i * 32, doff = (t & 7) * 8;
        uint4 vv = *(const uint4*)&sO[row * 72 + doff];
        *(uint4*)(Y + ((size_t)(b * 2048 + qt * 256 + row)) * 1024 + h16 * 64 + doff) = vv;
    }
#undef STAGE
}

// ---------------- launch ----------------

extern "C" void kernel_launch(void* const* d_in, const int* in_sizes, int n_in,
                              void* d_out, int out_size, void* d_ws, size_t ws_size,
                              hipStream_t stream) {
    const float* x = (const float*)d_in[0];
    const float* w_attn = (const float*)d_in[1];
    const float* w_proj = (const float*)d_in[2];
    float* out = (float*)d_out;
    char* ws = (char*)d_ws;

    bf16* xb = (bf16*)(ws);                    // 16 MiB; reused as Y after attention
    bf16* waT = (bf16*)(ws + 16777216);        // 6 MiB
    bf16* wpT = (bf16*)(ws + 23068672);        // 2 MiB
    bf16* qb = (bf16*)(ws + 25165824);         // 16 MiB
    bf16* kb = (bf16*)(ws + 41943040);         // 16 MiB
    bf16* vtb = (bf16*)(ws + 58720256);        // 16 MiB, transposed [B,H,D,N]

    cvt_f32_bf16<<<8192, 256, 0, stream>>>(x, (unsigned short*)xb, 2097152);
    transpose_bf16<<<dim3(96, 32), 256, 0, stream>>>(w_attn, (unsigned short*)waT, 1024, 3072);
    transpose_bf16<<<dim3(32, 32), 256, 0, stream>>>(w_proj, (unsigned short*)wpT, 1024, 1024);

    const float qscale = 0.125f * 1.44269504088896340736f;  // 1/sqrt(D) * log2(e)
    gemm_bf16<0><<<dim3(24, 64), 256, 0, stream>>>(xb, waT, (unsigned short*)qb,
                                                   (unsigned short*)kb, (unsigned short*)vtb,
                                                   nullptr, qscale);
    attn_kernel<<<dim3(512), 256, 0, stream>>>(qb, kb, vtb, xb /* Y reuses xb */);
    gemm_bf16<1><<<dim3(8, 64), 256, 0, stream>>>(xb, wpT, nullptr, nullptr, nullptr, out, 1.0f);
}